// Round 1
// baseline (1344.253 us; speedup 1.0000x reference)
//
#include <hip/hip_runtime.h>

// Row gather: out[i][:] = table[idx[i]][:], EMB_DIM = 128 floats = 512 B/row.
// 32 threads per row, each moving one float4 (16 B) -> 512 B contiguous per
// half-wave on both the gathered read and the streaming write.

#define EMB_VEC4 32  // 128 floats / 4 per float4

__global__ __launch_bounds__(256) void DistEmb_60842506715846_kernel(
    const float4* __restrict__ table,
    const int* __restrict__ idx,
    float4* __restrict__ out,
    int num_ids) {
    long long tid = (long long)blockIdx.x * blockDim.x + threadIdx.x;
    int row  = (int)(tid >> 5);   // which output row
    int lane = (int)(tid & 31);   // which float4 within the row
    if (row < num_ids) {
        long long src = (long long)idx[row] * EMB_VEC4 + lane;
        long long dst = (long long)row * EMB_VEC4 + lane;
        out[dst] = table[src];
    }
}

extern "C" void kernel_launch(void* const* d_in, const int* in_sizes, int n_in,
                              void* d_out, int out_size, void* d_ws, size_t ws_size,
                              hipStream_t stream) {
    const float4* table = (const float4*)d_in[0];
    const int*    idx   = (const int*)d_in[1];
    float4*       out   = (float4*)d_out;
    int num_ids = in_sizes[1];  // 1,048,576

    long long total_threads = (long long)num_ids * EMB_VEC4;
    int block = 256;
    int grid  = (int)((total_threads + block - 1) / block);
    DistEmb_60842506715846_kernel<<<grid, block, 0, stream>>>(table, idx, out, num_ids);
}